// Round 7
// baseline (22914.999 us; speedup 1.0000x reference)
//
#include <hip/hip_runtime.h>

typedef _Float16 half8 __attribute__((ext_vector_type(8)));
typedef float    f32x4 __attribute__((ext_vector_type(4)));
typedef unsigned u32;
typedef unsigned long long u64;
typedef unsigned u32x4 __attribute__((ext_vector_type(4)));

static constexpr int S_ = 2048;   // sequence length
static constexpr int B_ = 64;     // batch
static constexpr int D_ = 128;    // input dim
static constexpr int H_ = 256;    // hidden
static constexpr int C_ = 10;     // classes

static constexpr int NBLK = 64;   // 32 L1-role + 32 L2-role (R8 structure)
static constexpr int NTHR = 512;  // 8 waves (R8/R11-exact wave structure)
static constexpr int RU   = 3;    // u64 units per (colblk,batch) row
static constexpr int PLANE_U = 2048 * RU;   // u64 per plane-slot (48 KB)

// R15: epoch-embedded publish (self-validating data).
//   Each 8B unit = {3 or 2 fp16 halves} + 16-bit epoch in bits[63:48].
//   Producer: pack + relaxed agent stores -- NO vmcnt drain, NO flag.
//   Consumer: one asm batch load (vmcnt(0) inside, R11-proven) + epoch check,
//   retry until all units carry epoch lo16(base+t). This removes the drain RT,
//   the flag one-way leg and the separate poll RT from the critical cycle.
//   Rows are batch-major (row = batch*32 + colblk) so a lane's 8 K-tile rows
//   span 768B -> ONE base pointer + 13-bit signed offsets per plane.
//   WAR: lagged per-block progress flags g_f (target base+t before publish,
//   t>=3) bound producer/consumer skew to <=2 iters; satisfied ~2 iterations
//   early in steady state. Zero-init of h state deleted: t<=1 zero-state
//   fragments are compile-time zeros; epoch scheme makes prior-launch data
//   unmatchable (stale offsets -2050..-2 vs targets 0..+2049 mod 2^16).
__device__ __attribute__((aligned(64))) unsigned g_f[NBLK * 16];

#define LD_AG(p)    __hip_atomic_load((p), __ATOMIC_RELAXED, __HIP_MEMORY_SCOPE_AGENT)
#define ST_AG(p, v) __hip_atomic_store((p), (v), __ATOMIC_RELAXED, __HIP_MEMORY_SCOPE_AGENT)

__device__ __forceinline__ float fs(float v) { return 1.0f / (1.0f + __expf(-v)); }
__device__ __forceinline__ float ft(float v) { return 1.0f - 2.0f / (__expf(2.0f * v) + 1.0f); }

__device__ __forceinline__ half8 cvt8(float4 a, float4 b) {
    half8 r;
    r[0] = (_Float16)a.x; r[1] = (_Float16)a.y; r[2] = (_Float16)a.z; r[3] = (_Float16)a.w;
    r[4] = (_Float16)b.x; r[5] = (_Float16)b.y; r[6] = (_Float16)b.z; r[7] = (_Float16)b.w;
    return r;
}

// 8 rows from one plane: per row a 16B load (units 0,1) + 8B load (unit 2).
// Row stride 96B; all offsets fit the 13-bit signed immediate. vmcnt(0) inside
// the block (R11-proven soundness: nothing can observe un-landed outputs).
__device__ __forceinline__ void ldrows8(u32x4* q, u64* c, const u64* p)
{
    asm volatile(
        "global_load_dwordx4 %0, %16, off sc0 sc1\n\t"
        "global_load_dwordx2 %8, %16, off offset:16 sc0 sc1\n\t"
        "global_load_dwordx4 %1, %16, off offset:96 sc0 sc1\n\t"
        "global_load_dwordx2 %9, %16, off offset:112 sc0 sc1\n\t"
        "global_load_dwordx4 %2, %16, off offset:192 sc0 sc1\n\t"
        "global_load_dwordx2 %10, %16, off offset:208 sc0 sc1\n\t"
        "global_load_dwordx4 %3, %16, off offset:288 sc0 sc1\n\t"
        "global_load_dwordx2 %11, %16, off offset:304 sc0 sc1\n\t"
        "global_load_dwordx4 %4, %16, off offset:384 sc0 sc1\n\t"
        "global_load_dwordx2 %12, %16, off offset:400 sc0 sc1\n\t"
        "global_load_dwordx4 %5, %16, off offset:480 sc0 sc1\n\t"
        "global_load_dwordx2 %13, %16, off offset:496 sc0 sc1\n\t"
        "global_load_dwordx4 %6, %16, off offset:576 sc0 sc1\n\t"
        "global_load_dwordx2 %14, %16, off offset:592 sc0 sc1\n\t"
        "global_load_dwordx4 %7, %16, off offset:672 sc0 sc1\n\t"
        "global_load_dwordx2 %15, %16, off offset:688 sc0 sc1\n\t"
        "s_waitcnt vmcnt(0)"
        : "=&v"(q[0]), "=&v"(q[1]), "=&v"(q[2]), "=&v"(q[3]),
          "=&v"(q[4]), "=&v"(q[5]), "=&v"(q[6]), "=&v"(q[7]),
          "=&v"(c[0]), "=&v"(c[1]), "=&v"(c[2]), "=&v"(c[3]),
          "=&v"(c[4]), "=&v"(c[5]), "=&v"(c[6]), "=&v"(c[7])
        : "v"(p)
        : "memory");
}

// 16 rows (8 from plane A, 8 from plane B) in ONE block, ONE vmcnt(0).
__device__ __forceinline__ void ldrows16(u32x4* q, u64* c,
                                         const u64* pA, const u64* pB)
{
    asm volatile(
        "global_load_dwordx4 %0, %32, off sc0 sc1\n\t"
        "global_load_dwordx2 %16, %32, off offset:16 sc0 sc1\n\t"
        "global_load_dwordx4 %1, %32, off offset:96 sc0 sc1\n\t"
        "global_load_dwordx2 %17, %32, off offset:112 sc0 sc1\n\t"
        "global_load_dwordx4 %2, %32, off offset:192 sc0 sc1\n\t"
        "global_load_dwordx2 %18, %32, off offset:208 sc0 sc1\n\t"
        "global_load_dwordx4 %3, %32, off offset:288 sc0 sc1\n\t"
        "global_load_dwordx2 %19, %32, off offset:304 sc0 sc1\n\t"
        "global_load_dwordx4 %4, %32, off offset:384 sc0 sc1\n\t"
        "global_load_dwordx2 %20, %32, off offset:400 sc0 sc1\n\t"
        "global_load_dwordx4 %5, %32, off offset:480 sc0 sc1\n\t"
        "global_load_dwordx2 %21, %32, off offset:496 sc0 sc1\n\t"
        "global_load_dwordx4 %6, %32, off offset:576 sc0 sc1\n\t"
        "global_load_dwordx2 %22, %32, off offset:592 sc0 sc1\n\t"
        "global_load_dwordx4 %7, %32, off offset:672 sc0 sc1\n\t"
        "global_load_dwordx2 %23, %32, off offset:688 sc0 sc1\n\t"
        "global_load_dwordx4 %8, %33, off sc0 sc1\n\t"
        "global_load_dwordx2 %24, %33, off offset:16 sc0 sc1\n\t"
        "global_load_dwordx4 %9, %33, off offset:96 sc0 sc1\n\t"
        "global_load_dwordx2 %25, %33, off offset:112 sc0 sc1\n\t"
        "global_load_dwordx4 %10, %33, off offset:192 sc0 sc1\n\t"
        "global_load_dwordx2 %26, %33, off offset:208 sc0 sc1\n\t"
        "global_load_dwordx4 %11, %33, off offset:288 sc0 sc1\n\t"
        "global_load_dwordx2 %27, %33, off offset:304 sc0 sc1\n\t"
        "global_load_dwordx4 %12, %33, off offset:384 sc0 sc1\n\t"
        "global_load_dwordx2 %28, %33, off offset:400 sc0 sc1\n\t"
        "global_load_dwordx4 %13, %33, off offset:480 sc0 sc1\n\t"
        "global_load_dwordx2 %29, %33, off offset:496 sc0 sc1\n\t"
        "global_load_dwordx4 %14, %33, off offset:576 sc0 sc1\n\t"
        "global_load_dwordx2 %30, %33, off offset:592 sc0 sc1\n\t"
        "global_load_dwordx4 %15, %33, off offset:672 sc0 sc1\n\t"
        "global_load_dwordx2 %31, %33, off offset:688 sc0 sc1\n\t"
        "s_waitcnt vmcnt(0)"
        : "=&v"(q[0]),  "=&v"(q[1]),  "=&v"(q[2]),  "=&v"(q[3]),
          "=&v"(q[4]),  "=&v"(q[5]),  "=&v"(q[6]),  "=&v"(q[7]),
          "=&v"(q[8]),  "=&v"(q[9]),  "=&v"(q[10]), "=&v"(q[11]),
          "=&v"(q[12]), "=&v"(q[13]), "=&v"(q[14]), "=&v"(q[15]),
          "=&v"(c[0]),  "=&v"(c[1]),  "=&v"(c[2]),  "=&v"(c[3]),
          "=&v"(c[4]),  "=&v"(c[5]),  "=&v"(c[6]),  "=&v"(c[7]),
          "=&v"(c[8]),  "=&v"(c[9]),  "=&v"(c[10]), "=&v"(c[11]),
          "=&v"(c[12]), "=&v"(c[13]), "=&v"(c[14]), "=&v"(c[15])
        : "v"(pA), "v"(pB)
        : "memory");
}

// epoch-mismatch bits for one row (caller masks 0xffff0000 after OR-reduce)
__device__ __forceinline__ u32 rowbad(const u32x4 q, const u64 c, u32 et) {
    return (q.y ^ et) | (q.w ^ et) | ((u32)(c >> 32) ^ et);
}
// rebuild the contiguous half8 from units {h0,h1,h2,e}{h3,h4,h5,e}{h6,h7,-,e}
__device__ __forceinline__ half8 rowpack(const u32x4 q, const u64 c) {
    union { u32 d[4]; half8 h; } u;
    u.d[0] = q.x;
    u.d[1] = (q.y & 0xffffu) | (q.z << 16);
    u.d[2] = (q.z >> 16) | (q.w << 16);
    u.d[3] = (u32)c;
    return u.h;
}

__global__ __launch_bounds__(NTHR, 1)
void lstm2_ee(const float* __restrict__ x,
              const float* __restrict__ Wih1, const float* __restrict__ Whh1,
              const float* __restrict__ b1,
              const float* __restrict__ Wih2, const float* __restrict__ Whh2,
              const float* __restrict__ b2,
              const float* __restrict__ Wlin, const float* __restrict__ blin,
              float* __restrict__ out, _Float16* __restrict__ hb)
{
    const int bid = blockIdx.x, tid = threadIdx.x;
    const bool isL2 = (bid >= 32);
    const int blk  = bid & 31;                   // 0..31 within role
    const int lane = tid & 63, w = tid >> 6;     // 8 waves
    const int mt   = w & 3;                      // M-tile: batches mt*16..+15
    const int nt   = w >> 2;                     // N-tile 0/1
    const int n    = lane & 15;                  // n-row within tile
    const int kg   = lane >> 4;                  // k-group 0..3
    const int c4   = n >> 2, gate = n & 3;       // n = col4*4 + gate
    const int lc   = nt * 4 + c4;                // local col 0..7
    const int col  = blk * 8 + lc;               // hidden column 0..255
    const int rowg = gate * H_ + col;            // global W gate-row
    const int batchA = mt * 16 + n;              // A-frag row = batch

    u64* hb64 = (u64*)hb;
    // plane-slot bases (u64 index): h1raw: 0+s, h1t: 3+s, h2raw: 6+s, h2t: 9+s
    const int rowoff = (batchA * 32 + kg) * RU;  // consumer base row offset

    __shared__ __align__(16) _Float16 sh[2][B_][8];   // [raw|tanh][batch][local col]

    const unsigned base = LD_AG(&g_f[bid * 16]);   // uniform at launch boundary

    // ---- weight-stationary B-fragments in VGPRs (loaded once; R8-verbatim) ----
    half8 bfrag[16];
    if (!isL2) {
        #pragma unroll
        for (int kt = 0; kt < 4; ++kt) {     // Wih1 [4H][128]
            const float* p = Wih1 + (size_t)rowg * D_ + kt * 32 + kg * 8;
            bfrag[kt] = cvt8(*(const float4*)p, *(const float4*)(p + 4));
        }
        #pragma unroll
        for (int kt = 4; kt < 12; ++kt) {    // Whh1 [4H][256]
            const float* p = Whh1 + (size_t)rowg * H_ + (kt - 4) * 32 + kg * 8;
            bfrag[kt] = cvt8(*(const float4*)p, *(const float4*)(p + 4));
        }
    } else {
        #pragma unroll
        for (int kt = 0; kt < 8; ++kt) {     // Wih2 [4H][256]
            const float* p = Wih2 + (size_t)rowg * H_ + kt * 32 + kg * 8;
            bfrag[kt] = cvt8(*(const float4*)p, *(const float4*)(p + 4));
        }
        #pragma unroll
        for (int kt = 8; kt < 16; ++kt) {    // Whh2 [4H][256]
            const float* p = Whh2 + (size_t)rowg * H_ + (kt - 8) * 32 + kg * 8;
            bfrag[kt] = cvt8(*(const float4*)p, *(const float4*)(p + 4));
        }
    }
    const float bias_n = isL2 ? b2[rowg] : b1[rowg];

    float cr[4] = {0.f, 0.f, 0.f, 0.f};   // cell state

    // x prefetch registers (L1 blocks only): first float4 of each K-tile
    float4 xf0, xf1, xf2, xf3;
    if (!isL2) {
        const float* xr = x + (size_t)batchA * D_;   // t = 0
        xf0 = *(const float4*)(xr + (kg * 8));
        xf1 = *(const float4*)(xr + (32 + kg * 8));
        xf2 = *(const float4*)(xr + (64 + kg * 8));
        xf3 = *(const float4*)(xr + (96 + kg * 8));
    }

    int w3 = 0;   // t % 3

    // iteration t: L1 computes h1[t] (slot w3); L2 computes h2[t-1] (slot r1)
    // reading h1t[r1] (epoch base+t) and h2raw[r2] (also epoch base+t: h2[t-2]
    // was published at iter t-1); head computes out[t-2] from h2t[r2].
    for (int t = 0; t <= S_ + 1; ++t) {
        const int r1 = (w3 == 0) ? 2 : w3 - 1;   // (t-1) % 3
        const int r2 = (w3 == 2) ? 0 : w3 + 1;   // (t-2) % 3
        const u32 et1 = ((base + (u32)t) & 0xffffu) << 16;   // all consumer targets

        if (!isL2) {
            if (t < S_) {
                half8 af[12];
                {   // x part: prefetched first half + fresh second half
                    const float* xr = x + ((size_t)t * B_ + batchA) * D_;
                    af[0] = cvt8(xf0, *(const float4*)(xr + (kg * 8) + 4));
                    af[1] = cvt8(xf1, *(const float4*)(xr + (32 + kg * 8) + 4));
                    af[2] = cvt8(xf2, *(const float4*)(xr + (64 + kg * 8) + 4));
                    af[3] = cvt8(xf3, *(const float4*)(xr + (96 + kg * 8) + 4));
                }
                if (t == 0) {
                    union { u32 d[4]; half8 h; } Z; Z.d[0]=Z.d[1]=Z.d[2]=Z.d[3]=0;
                    #pragma unroll
                    for (int kt = 0; kt < 8; ++kt) af[4 + kt] = Z.h;
                } else {
                    const u64* pA = hb64 + (size_t)(0 + r1) * PLANE_U + rowoff;
                    u32x4 q[8]; u64 c[8]; u32 bad;
                    do {
                        ldrows8(q, c, pA);
                        bad = 0;
                        #pragma unroll
                        for (int kt = 0; kt < 8; ++kt) bad |= rowbad(q[kt], c[kt], et1);
                        bad &= 0xffff0000u;
                    } while (__any(bad != 0));
                    #pragma unroll
                    for (int kt = 0; kt < 8; ++kt) af[4 + kt] = rowpack(q[kt], c[kt]);
                }
                f32x4 accA = {0.f, 0.f, 0.f, 0.f}, accB = {0.f, 0.f, 0.f, 0.f};
                #pragma unroll
                for (int kt = 0; kt < 12; kt += 2) {
                    accA = __builtin_amdgcn_mfma_f32_16x16x32_f16(af[kt],     bfrag[kt],     accA, 0, 0, 0);
                    accB = __builtin_amdgcn_mfma_f32_16x16x32_f16(af[kt + 1], bfrag[kt + 1], accB, 0, 0, 0);
                }
                #pragma unroll
                for (int r = 0; r < 4; ++r) {
                    const float pre = accA[r] + accB[r] + bias_n;
                    const float av  = (gate == 2) ? ft(pre) : fs(pre);
                    const int lb = (lane & 48) | (c4 << 2);
                    const float gi = __shfl(av, lb | 0, 64), gf = __shfl(av, lb | 1, 64);
                    const float gg = __shfl(av, lb | 2, 64), go = __shfl(av, lb | 3, 64);
                    const float cn = gf * cr[r] + gi * gg; cr[r] = cn;
                    const float hv = go * ft(cn);
                    const int bD = mt * 16 + kg * 4 + r;
                    if (gate == 0) sh[0][bD][lc] = (_Float16)hv;
                    if (gate == 1) sh[1][bD][lc] = (_Float16)ft(hv);
                }
            }
        } else {
            if (t >= 1 && t <= S_) {
                half8 af[16];
                if (t == 1) {
                    const u64* pA = hb64 + (size_t)(3 + r1) * PLANE_U + rowoff;
                    u32x4 q[8]; u64 c[8]; u32 bad;
                    do {
                        ldrows8(q, c, pA);
                        bad = 0;
                        #pragma unroll
                        for (int kt = 0; kt < 8; ++kt) bad |= rowbad(q[kt], c[kt], et1);
                        bad &= 0xffff0000u;
                    } while (__any(bad != 0));
                    #pragma unroll
                    for (int kt = 0; kt < 8; ++kt) af[kt] = rowpack(q[kt], c[kt]);
                    union { u32 d[4]; half8 h; } Z; Z.d[0]=Z.d[1]=Z.d[2]=Z.d[3]=0;
                    #pragma unroll
                    for (int kt = 0; kt < 8; ++kt) af[8 + kt] = Z.h;
                } else {
                    const u64* pA = hb64 + (size_t)(3 + r1) * PLANE_U + rowoff;
                    const u64* pB = hb64 + (size_t)(6 + r2) * PLANE_U + rowoff;
                    u32x4 q[16]; u64 c[16]; u32 bad;
                    do {
                        ldrows16(q, c, pA, pB);
                        bad = 0;
                        #pragma unroll
                        for (int kt = 0; kt < 16; ++kt) bad |= rowbad(q[kt], c[kt], et1);
                        bad &= 0xffff0000u;
                    } while (__any(bad != 0));
                    #pragma unroll
                    for (int kt = 0; kt < 16; ++kt) af[kt] = rowpack(q[kt], c[kt]);
                }
                f32x4 accA = {0.f, 0.f, 0.f, 0.f}, accB = {0.f, 0.f, 0.f, 0.f};
                #pragma unroll
                for (int kt = 0; kt < 16; kt += 2) {
                    accA = __builtin_amdgcn_mfma_f32_16x16x32_f16(af[kt],     bfrag[kt],     accA, 0, 0, 0);
                    accB = __builtin_amdgcn_mfma_f32_16x16x32_f16(af[kt + 1], bfrag[kt + 1], accB, 0, 0, 0);
                }
                #pragma unroll
                for (int r = 0; r < 4; ++r) {
                    const float pre = accA[r] + accB[r] + bias_n;
                    const float av  = (gate == 2) ? ft(pre) : fs(pre);
                    const int lb = (lane & 48) | (c4 << 2);
                    const float gi = __shfl(av, lb | 0, 64), gf = __shfl(av, lb | 1, 64);
                    const float gg = __shfl(av, lb | 2, 64), go = __shfl(av, lb | 3, 64);
                    const float cn = gf * cr[r] + gi * gg; cr[r] = cn;
                    const float hv = go * ft(cn);
                    const int bD = mt * 16 + kg * 4 + r;
                    if (gate == 0) sh[0][bD][lc] = (_Float16)hv;
                    if (gate == 1) sh[1][bD][lc] = (_Float16)ft(hv);
                }
            }
        }

        __syncthreads();   // sh tile complete; all reads of this iter's data done

        // progress flag (reads-done marker, NOT data-ready): no drain needed
        if (tid == 0) ST_AG(&g_f[bid * 16], base + (u32)t + 2u);

        // ---- publish (wave 0): WAR guard + pack + fire-and-forget stores ----
        if (tid < 64) {
            bool doit; int slot;
            if (!isL2) { doit = (t < S_);            slot = w3; }
            else       { doit = (t >= 1 && t <= S_); slot = r1; }
            if (doit) {
                if (t >= 3) {   // peers finished iter t-2 => old slot data consumed
                    const u32 tg = base + (u32)t;
                    while ((int)(LD_AG(&g_f[tid * 16]) - tg) < 0) {}
                }
                const u32 etp = ((base + (u32)t + 1u) & 0xffffu) << 16;
                const u32* s0 = (const u32*)&sh[0][tid][0];
                const u32* s1 = (const u32*)&sh[1][tid][0];
                const int prow = (tid * 32 + blk) * RU;
                u64* d0 = hb64 + (size_t)((isL2 ? 6 : 0) + slot) * PLANE_U + prow;
                u64* d1 = hb64 + (size_t)((isL2 ? 9 : 3) + slot) * PLANE_U + prow;
                {
                    const u32 a = s0[0], b2 = s0[1], c2 = s0[2], dd = s0[3];
                    ST_AG(d0 + 0, (u64)a | ((u64)((b2 & 0xffffu) | etp) << 32));
                    ST_AG(d0 + 1, (u64)((b2 >> 16) | (c2 << 16)) | ((u64)((c2 >> 16) | etp) << 32));
                    ST_AG(d0 + 2, (u64)dd | ((u64)etp << 32));
                }
                {
                    const u32 a = s1[0], b2 = s1[1], c2 = s1[2], dd = s1[3];
                    ST_AG(d1 + 0, (u64)a | ((u64)((b2 & 0xffffu) | etp) << 32));
                    ST_AG(d1 + 1, (u64)((b2 >> 16) | (c2 << 16)) | ((u64)((c2 >> 16) | etp) << 32));
                    ST_AG(d1 + 2, (u64)dd | ((u64)etp << 32));
                }
            }
        }

        // ---- post-publish work ----
        // x prefetch for t+1 (L1 role)
        if (!isL2 && t + 1 < S_) {
            const float* xr = x + ((size_t)(t + 1) * B_ + batchA) * D_;
            xf0 = *(const float4*)(xr + (kg * 8));
            xf1 = *(const float4*)(xr + (32 + kg * 8));
            xf2 = *(const float4*)(xr + (64 + kg * 8));
            xf3 = *(const float4*)(xr + (96 + kg * 8));
        }
        // head (on L2): out[t-2] = sigmoid(tanh(h2[t-2]) @ Wlin^T + blin)
        if (isL2 && t >= 2) {
            const int g16 = tid >> 4;
            if (g16 < 20) {
                const int dot = blk * 20 + g16, cls = dot >> 6, ob = dot & 63, l16 = tid & 15;
                const u64* hp = hb64 + (size_t)(9 + r2) * PLANE_U + (ob * 32 + 2 * l16) * RU;
                u64 v[6]; u32 bad;
                do {
                    #pragma unroll
                    for (int j = 0; j < 6; ++j) v[j] = LD_AG(hp + j);
                    bad = 0;
                    #pragma unroll
                    for (int j = 0; j < 6; ++j) bad |= ((u32)(v[j] >> 32)) ^ et1;
                    bad &= 0xffff0000u;
                } while (bad != 0);
                union { u32 d[4]; half8 h; } A, Bv;
                A.d[0] = (u32)v[0];
                A.d[1] = ((u32)(v[0] >> 32) & 0xffffu) | ((u32)v[1] << 16);
                A.d[2] = ((u32)v[1] >> 16) | ((u32)(v[1] >> 32) << 16);
                A.d[3] = (u32)v[2];
                Bv.d[0] = (u32)v[3];
                Bv.d[1] = ((u32)(v[3] >> 32) & 0xffffu) | ((u32)v[4] << 16);
                Bv.d[2] = ((u32)v[4] >> 16) | ((u32)(v[4] >> 32) << 16);
                Bv.d[3] = (u32)v[5];
                const float* wr = Wlin + (size_t)cls * H_ + l16 * 16;
                float p = 0.f;
                #pragma unroll
                for (int j = 0; j < 8; ++j)
                    p += (float)A.h[j] * wr[j] + (float)Bv.h[j] * wr[8 + j];
                p += __shfl_xor(p, 1, 64); p += __shfl_xor(p, 2, 64);
                p += __shfl_xor(p, 4, 64); p += __shfl_xor(p, 8, 64);
                if (l16 == 0)
                    out[((size_t)(t - 2) * B_ + ob) * C_ + cls] = fs(p + blin[cls]);
            }
        }

        __syncthreads();   // sh protected until wave-0 publish read it

        w3 = r2;   // (t+1) % 3
    }
}

extern "C" void kernel_launch(void* const* d_in, const int* in_sizes, int n_in,
                              void* d_out, int out_size, void* d_ws, size_t ws_size,
                              hipStream_t stream)
{
    const float* x    = (const float*)d_in[0];
    const float* Wih1 = (const float*)d_in[1];
    const float* Whh1 = (const float*)d_in[2];
    const float* b1   = (const float*)d_in[3];
    const float* Wih2 = (const float*)d_in[4];
    const float* Whh2 = (const float*)d_in[5];
    const float* b2   = (const float*)d_in[6];
    const float* Wlin = (const float*)d_in[7];
    const float* blin = (const float*)d_in[8];
    float* out = (float*)d_out;
    _Float16* hb = (_Float16*)d_ws;

    void* args[] = { (void*)&x, (void*)&Wih1, (void*)&Whh1, (void*)&b1,
                     (void*)&Wih2, (void*)&Whh2, (void*)&b2,
                     (void*)&Wlin, (void*)&blin, (void*)&out, (void*)&hb };
    hipLaunchCooperativeKernel((const void*)lstm2_ee, dim3(NBLK), dim3(NTHR),
                               args, 0, stream);
}

// Round 8
// 9233.038 us; speedup vs baseline: 2.4818x; 2.4818x over previous
//
#include <hip/hip_runtime.h>

typedef _Float16 half8 __attribute__((ext_vector_type(8)));
typedef float    f32x4 __attribute__((ext_vector_type(4)));

static constexpr int S_ = 2048;   // sequence length
static constexpr int B_ = 64;     // batch
static constexpr int D_ = 128;    // input dim
static constexpr int H_ = 256;    // hidden
static constexpr int C_ = 10;     // classes

static constexpr int NBLK = 64;   // 32 L1-role + 32 L2-role (R8 structure)
static constexpr int NTHR = 512;  // 8 waves (R8/R11-exact wave structure)
static constexpr int HHALF = B_ * H_;   // halves per h slot (32 KB)

// R16 = R14 (best, 9405 us) + two chain cuts, zero protocol change:
//  (1) FULL x prefetch (8 float4/lane instead of 4): R14 loaded the second
//      half of each x fragment inside the compute phase; the compiler's
//      waitcnt for those loads serialized BEFORE the h-load asm block.
//      All-register af[0..3] removes one L2 RT from L1's critical chain.
//  (2) s_sleep(1) backoff after a FAILED flag poll: 64 lanes/line spin
//      continuously otherwise; hot-line LLC contention slows both detect
//      and peer loads. Success path (steady state) unaffected.
//
// Per-block epoch flags, one 64B line each (R7/R8-proven).
__device__ __attribute__((aligned(64))) unsigned g_f[NBLK * 16];

#define LD_AG(p)    __hip_atomic_load((p), __ATOMIC_RELAXED, __HIP_MEMORY_SCOPE_AGENT)
#define ST_AG(p, v) __hip_atomic_store((p), (v), __ATOMIC_RELAXED, __HIP_MEMORY_SCOPE_AGENT)

__device__ __forceinline__ float fs(float v) { return 1.0f / (1.0f + __expf(-v)); }
__device__ __forceinline__ float ft(float v) { return 1.0f - 2.0f / (__expf(2.0f * v) + 1.0f); }

// device-scope (LLC-coherent) 16B load of 8 halves as two 8B relaxed atomics
// (kept for the low-volume head path)
__device__ __forceinline__ half8 ldh16(const _Float16* p) {
    union { double d[2]; half8 h; } u;
    u.d[0] = LD_AG((const double*)p);
    u.d[1] = LD_AG(((const double*)p) + 1);
    return u.h;
}

// 8x 16B LLC-coherent loads in ONE asm block, completed by the trailing
// vmcnt(0): the compiler/RA can never read an un-landed destination register.
__device__ __forceinline__ void ldg16x8(half8* r,
    const _Float16* p0, const _Float16* p1, const _Float16* p2, const _Float16* p3,
    const _Float16* p4, const _Float16* p5, const _Float16* p6, const _Float16* p7)
{
    asm volatile(
        "global_load_dwordx4 %0, %8, off sc0 sc1\n\t"
        "global_load_dwordx4 %1, %9, off sc0 sc1\n\t"
        "global_load_dwordx4 %2, %10, off sc0 sc1\n\t"
        "global_load_dwordx4 %3, %11, off sc0 sc1\n\t"
        "global_load_dwordx4 %4, %12, off sc0 sc1\n\t"
        "global_load_dwordx4 %5, %13, off sc0 sc1\n\t"
        "global_load_dwordx4 %6, %14, off sc0 sc1\n\t"
        "global_load_dwordx4 %7, %15, off sc0 sc1\n\t"
        "s_waitcnt vmcnt(0)"
        : "=&v"(r[0]), "=&v"(r[1]), "=&v"(r[2]), "=&v"(r[3]),
          "=&v"(r[4]), "=&v"(r[5]), "=&v"(r[6]), "=&v"(r[7])
        : "v"(p0), "v"(p1), "v"(p2), "v"(p3),
          "v"(p4), "v"(p5), "v"(p6), "v"(p7)
        : "memory");
}

// 16x 16B LLC-coherent loads (8 fragments from pa, 8 from pb; fragment stride
// 2048 halves = 4096 B) in ONE asm block with ONE trailing vmcnt(0) -- a single
// LLC round-trip for the whole L2 operand set (R14-proven).
__device__ __forceinline__ void ldg16x8x2(half8* r,
                                          const _Float16* pa, const _Float16* pb)
{
    const _Float16* a0 = pa + 2048;  const _Float16* a1 = pa + 6144;
    const _Float16* a2 = pa + 10240; const _Float16* a3 = pa + 14336;
    const _Float16* b0 = pb + 2048;  const _Float16* b1 = pb + 6144;
    const _Float16* b2 = pb + 10240; const _Float16* b3 = pb + 14336;
    asm volatile(
        "global_load_dwordx4 %0, %16, off offset:-4096 sc0 sc1\n\t"
        "global_load_dwordx4 %1, %16, off sc0 sc1\n\t"
        "global_load_dwordx4 %2, %17, off offset:-4096 sc0 sc1\n\t"
        "global_load_dwordx4 %3, %17, off sc0 sc1\n\t"
        "global_load_dwordx4 %4, %18, off offset:-4096 sc0 sc1\n\t"
        "global_load_dwordx4 %5, %18, off sc0 sc1\n\t"
        "global_load_dwordx4 %6, %19, off offset:-4096 sc0 sc1\n\t"
        "global_load_dwordx4 %7, %19, off sc0 sc1\n\t"
        "global_load_dwordx4 %8, %20, off offset:-4096 sc0 sc1\n\t"
        "global_load_dwordx4 %9, %20, off sc0 sc1\n\t"
        "global_load_dwordx4 %10, %21, off offset:-4096 sc0 sc1\n\t"
        "global_load_dwordx4 %11, %21, off sc0 sc1\n\t"
        "global_load_dwordx4 %12, %22, off offset:-4096 sc0 sc1\n\t"
        "global_load_dwordx4 %13, %22, off sc0 sc1\n\t"
        "global_load_dwordx4 %14, %23, off offset:-4096 sc0 sc1\n\t"
        "global_load_dwordx4 %15, %23, off sc0 sc1\n\t"
        "s_waitcnt vmcnt(0)"
        : "=&v"(r[0]),  "=&v"(r[1]),  "=&v"(r[2]),  "=&v"(r[3]),
          "=&v"(r[4]),  "=&v"(r[5]),  "=&v"(r[6]),  "=&v"(r[7]),
          "=&v"(r[8]),  "=&v"(r[9]),  "=&v"(r[10]), "=&v"(r[11]),
          "=&v"(r[12]), "=&v"(r[13]), "=&v"(r[14]), "=&v"(r[15])
        : "v"(a0), "v"(a1), "v"(a2), "v"(a3),
          "v"(b0), "v"(b1), "v"(b2), "v"(b3)
        : "memory");
}

// 16B LLC-coherent store (publish path; R12/R14-verified). The caller's
// trailing s_waitcnt vmcnt(0) orders it before the flag store.
__device__ __forceinline__ void stg16(_Float16* p, half8 v) {
    asm volatile("global_store_dwordx4 %0, %1, off sc0 sc1"
                 :: "v"(p), "v"(v) : "memory");
}

__device__ __forceinline__ half8 cvt8(float4 a, float4 b) {
    half8 r;
    r[0] = (_Float16)a.x; r[1] = (_Float16)a.y; r[2] = (_Float16)a.z; r[3] = (_Float16)a.w;
    r[4] = (_Float16)b.x; r[5] = (_Float16)b.y; r[6] = (_Float16)b.z; r[7] = (_Float16)b.w;
    return r;
}

__global__ __launch_bounds__(NTHR, 1)
void lstm2_ef(const float* __restrict__ x,
              const float* __restrict__ Wih1, const float* __restrict__ Whh1,
              const float* __restrict__ b1,
              const float* __restrict__ Wih2, const float* __restrict__ Whh2,
              const float* __restrict__ b2,
              const float* __restrict__ Wlin, const float* __restrict__ blin,
              float* __restrict__ out, _Float16* __restrict__ hb)
{
    const int bid = blockIdx.x, tid = threadIdx.x;
    const bool isL2 = (bid >= 32);
    const int blk  = bid & 31;                   // 0..31 within role
    const int lane = tid & 63, w = tid >> 6;     // 8 waves
    const int mt   = w & 3;                      // M-tile: batches mt*16..+15
    const int nt   = w >> 2;                     // N-tile 0/1
    const int n    = lane & 15;                  // n-row within tile
    const int kg   = lane >> 4;                  // k-group 0..3
    const int c4   = n >> 2, gate = n & 3;       // n = col4*4 + gate
    const int lc   = nt * 4 + c4;                // local col 0..7
    const int col  = blk * 8 + lc;               // hidden column 0..255
    const int rowg = gate * H_ + col;            // global W gate-row
    const int batchA = mt * 16 + n;              // A-frag row = batch

    _Float16* h1raw = hb;                 // [3][HHALF] each
    _Float16* h1t   = hb + 3 * HHALF;
    _Float16* h2raw = hb + 6 * HHALF;
    _Float16* h2t   = hb + 9 * HHALF;

    __shared__ __align__(16) _Float16 sh[2][B_][8];   // [raw|tanh][batch][local col]

    const unsigned base = LD_AG(&g_f[bid * 16]);   // uniform at launch boundary

    // zero h state via agent-scope stores: 12 slots * 32 KB = 49152 doubles
    { double* z = (double*)hb;
      for (int i = bid * NTHR + tid; i < 49152; i += NBLK * NTHR) ST_AG(z + i, 0.0); }

    // ---- weight-stationary B-fragments in VGPRs (loaded once; R8-verbatim) ----
    half8 bfrag[16];
    if (!isL2) {
        #pragma unroll
        for (int kt = 0; kt < 4; ++kt) {     // Wih1 [4H][128]
            const float* p = Wih1 + (size_t)rowg * D_ + kt * 32 + kg * 8;
            bfrag[kt] = cvt8(*(const float4*)p, *(const float4*)(p + 4));
        }
        #pragma unroll
        for (int kt = 4; kt < 12; ++kt) {    // Whh1 [4H][256]
            const float* p = Whh1 + (size_t)rowg * H_ + (kt - 4) * 32 + kg * 8;
            bfrag[kt] = cvt8(*(const float4*)p, *(const float4*)(p + 4));
        }
    } else {
        #pragma unroll
        for (int kt = 0; kt < 8; ++kt) {     // Wih2 [4H][256]
            const float* p = Wih2 + (size_t)rowg * H_ + kt * 32 + kg * 8;
            bfrag[kt] = cvt8(*(const float4*)p, *(const float4*)(p + 4));
        }
        #pragma unroll
        for (int kt = 8; kt < 16; ++kt) {    // Whh2 [4H][256]
            const float* p = Whh2 + (size_t)rowg * H_ + (kt - 8) * 32 + kg * 8;
            bfrag[kt] = cvt8(*(const float4*)p, *(const float4*)(p + 4));
        }
    }
    const float bias_n = isL2 ? b2[rowg] : b1[rowg];

    // publish init (zero-state visible): all waves' zero stores must be acked
    __syncthreads();                 // full-block vmcnt(0) drain before barrier
    if (tid == 0) ST_AG(&g_f[bid * 16], base + 1u);

    float cr[4] = {0.f, 0.f, 0.f, 0.f};   // cell state

    // x prefetch registers (L1 blocks only): FULL x fragments for t
    // xf[2q] / xf[2q+1] = first/second float4 of K-tile q. 32 VGPRs.
    float4 xf[8];
    if (!isL2) {
        const float* xr = x + (size_t)batchA * D_;   // t = 0
        #pragma unroll
        for (int q = 0; q < 4; ++q) {
            xf[2 * q]     = *(const float4*)(xr + q * 32 + kg * 8);
            xf[2 * q + 1] = *(const float4*)(xr + q * 32 + kg * 8 + 4);
        }
    }

    int w3 = 0;   // t % 3

    // iteration t: L1 computes h1[t] (slot w3); L2 computes h2[t-1] (slot r1)
    // reading h1t[r1], h2raw[r2]; head (on L2) computes out[t-2] from h2t[r2].
    for (int t = 0; t <= S_ + 1; ++t) {
        const int r1 = (w3 == 0) ? 2 : w3 - 1;   // (t-1) % 3
        const int r2 = (w3 == 2) ? 0 : w3 + 1;   // (t-2) % 3

        // ---- p2p flag wait: lane l polls block l's flag ----
        // L1 needs: F(L1 peers) >= base+t+1 (data), F(L2) >= base+t (WAR, NB=3);
        // at t==0 L1 also waits L2 at t+1 (zero-init written by ALL blocks).
        // L2 needs: F(all) >= base+t+1 (data)
        {
            const unsigned et1 = base + (unsigned)t + 1u;
            if (tid < 64) {
                const unsigned tg = (tid < 32 || isL2 || t == 0) ? et1 : et1 - 1u;
                while ((int)(LD_AG(&g_f[tid * 16]) - tg) < 0)
                    __builtin_amdgcn_s_sleep(1);   // backoff: cut hot-line polls
            }
            __syncthreads();
        }

        if (!isL2) {
            if (t < S_) {
                half8 af[12];
                {   // x part: ALL from prefetch registers (no loads on chain)
                    af[0] = cvt8(xf[0], xf[1]);
                    af[1] = cvt8(xf[2], xf[3]);
                    af[2] = cvt8(xf[4], xf[5]);
                    af[3] = cvt8(xf[6], xf[7]);
                }
                // h part: K-tile (kt,kg) -> block region jb = kt*4+kg;
                // kt stride in halves = 4*64*8 = 2048
                const _Float16* hp = h1raw + r1 * HHALF + (((size_t)kg * 64 + batchA) << 3);
                ldg16x8(&af[4], hp,          hp + 2048,  hp + 4096,  hp + 6144,
                                hp + 8192,   hp + 10240, hp + 12288, hp + 14336);
                f32x4 accA = {0.f, 0.f, 0.f, 0.f}, accB = {0.f, 0.f, 0.f, 0.f};
                #pragma unroll
                for (int kt = 0; kt < 12; kt += 2) {
                    accA = __builtin_amdgcn_mfma_f32_16x16x32_f16(af[kt],     bfrag[kt],     accA, 0, 0, 0);
                    accB = __builtin_amdgcn_mfma_f32_16x16x32_f16(af[kt + 1], bfrag[kt + 1], accB, 0, 0, 0);
                }
                #pragma unroll
                for (int r = 0; r < 4; ++r) {
                    const float pre = accA[r] + accB[r] + bias_n;
                    const float av  = (gate == 2) ? ft(pre) : fs(pre);
                    const int lb = (lane & 48) | (c4 << 2);
                    const float gi = __shfl(av, lb | 0, 64), gf = __shfl(av, lb | 1, 64);
                    const float gg = __shfl(av, lb | 2, 64), go = __shfl(av, lb | 3, 64);
                    const float cn = gf * cr[r] + gi * gg; cr[r] = cn;
                    const float hv = go * ft(cn);
                    const int bD = mt * 16 + kg * 4 + r;
                    if (gate == 0) sh[0][bD][lc] = (_Float16)hv;
                    if (gate == 1) sh[1][bD][lc] = (_Float16)ft(hv);
                }
            }
        } else {
            if (t >= 1 && t <= S_) {
                half8 af[16];
                const _Float16* h1p = h1t   + r1 * HHALF + (((size_t)kg * 64 + batchA) << 3);
                const _Float16* h2p = h2raw + r2 * HHALF + (((size_t)kg * 64 + batchA) << 3);
                ldg16x8x2(af, h1p, h2p);   // all 16 fragments, ONE vmcnt(0)
                f32x4 accA = {0.f, 0.f, 0.f, 0.f}, accB = {0.f, 0.f, 0.f, 0.f};
                #pragma unroll
                for (int kt = 0; kt < 16; kt += 2) {
                    accA = __builtin_amdgcn_mfma_f32_16x16x32_f16(af[kt],     bfrag[kt],     accA, 0, 0, 0);
                    accB = __builtin_amdgcn_mfma_f32_16x16x32_f16(af[kt + 1], bfrag[kt + 1], accB, 0, 0, 0);
                }
                #pragma unroll
                for (int r = 0; r < 4; ++r) {
                    const float pre = accA[r] + accB[r] + bias_n;
                    const float av  = (gate == 2) ? ft(pre) : fs(pre);
                    const int lb = (lane & 48) | (c4 << 2);
                    const float gi = __shfl(av, lb | 0, 64), gf = __shfl(av, lb | 1, 64);
                    const float gg = __shfl(av, lb | 2, 64), go = __shfl(av, lb | 3, 64);
                    const float cn = gf * cr[r] + gi * gg; cr[r] = cn;
                    const float hv = go * ft(cn);
                    const int bD = mt * 16 + kg * 4 + r;
                    if (gate == 0) sh[0][bD][lc] = (_Float16)hv;
                    if (gate == 1) sh[1][bD][lc] = (_Float16)ft(hv);
                }
            }
        }

        __syncthreads();   // LDS tile complete (lgkm drain + barrier)

        // ---- single-wave publish + EARLY FLAG (wave 0 only) ----
        // Wave 0 stores the block's full 2KB output; its own s_waitcnt vmcnt(0)
        // covers all publish stores (wave-wide); lane 0 then stores the flag.
        // No block barrier between publish and flag.
        if (tid < 64) {
            const int b = tid;
            bool doit; int slot;
            if (!isL2) { doit = (t < S_);            slot = w3; }
            else       { doit = (t >= 1 && t <= S_); slot = r1; }
            if (doit) {
                const half8 s0 = *(const half8*)&sh[0][b][0];
                const half8 s1 = *(const half8*)&sh[1][b][0];
                _Float16* braw = isL2 ? h2raw : h1raw;
                _Float16* btnh = isL2 ? h2t   : h1t;
                stg16(braw + slot * HHALF + ((blk * 64 + b) << 3), s0);
                stg16(btnh + slot * HHALF + ((blk * 64 + b) << 3), s1);
            }
            asm volatile("s_waitcnt vmcnt(0)" ::: "memory");
            __builtin_amdgcn_sched_barrier(0);
            if (tid == 0) ST_AG(&g_f[bid * 16], base + (unsigned)t + 2u);
        }

        // ---- post-flag work: overlaps peers' detect+load window ----
        // x prefetch for t+1 (L1 role): FULL fragments
        if (!isL2 && t + 1 < S_) {
            const float* xr = x + ((size_t)(t + 1) * B_ + batchA) * D_;
            #pragma unroll
            for (int q = 0; q < 4; ++q) {
                xf[2 * q]     = *(const float4*)(xr + q * 32 + kg * 8);
                xf[2 * q + 1] = *(const float4*)(xr + q * 32 + kg * 8 + 4);
            }
        }
        // head (on L2): out[t-2] = sigmoid(tanh(h2[t-2]) @ Wlin^T + blin)
        if (isL2 && t >= 2) {
            const int g16 = tid >> 4;
            if (g16 < 20) {
                const int dot = blk * 20 + g16, cls = dot >> 6, ob = dot & 63, l16 = tid & 15;
                const _Float16* hB = h2t + r2 * HHALF;
                const half8 v0 = ldh16(hB + (((2 * l16)     * 64 + ob) << 3));
                const half8 v1 = ldh16(hB + (((2 * l16 + 1) * 64 + ob) << 3));
                const float* wr = Wlin + (size_t)cls * H_ + l16 * 16;
                float p = 0.f;
                #pragma unroll
                for (int j = 0; j < 8; ++j) p += (float)v0[j] * wr[j] + (float)v1[j] * wr[8 + j];
                p += __shfl_xor(p, 1, 64); p += __shfl_xor(p, 2, 64);
                p += __shfl_xor(p, 4, 64); p += __shfl_xor(p, 8, 64);
                if (l16 == 0)
                    out[((size_t)(t - 2) * B_ + ob) * C_ + cls] = fs(p + blin[cls]);
            }
        }
        // no end-of-iteration barrier: next iteration's flag-wait barrier
        // orders LDS-tile reuse (writes happen only after all waves pass it).

        w3 = r2;   // (t+1) % 3
    }
}

extern "C" void kernel_launch(void* const* d_in, const int* in_sizes, int n_in,
                              void* d_out, int out_size, void* d_ws, size_t ws_size,
                              hipStream_t stream)
{
    const float* x    = (const float*)d_in[0];
    const float* Wih1 = (const float*)d_in[1];
    const float* Whh1 = (const float*)d_in[2];
    const float* b1   = (const float*)d_in[3];
    const float* Wih2 = (const float*)d_in[4];
    const float* Whh2 = (const float*)d_in[5];
    const float* b2   = (const float*)d_in[6];
    const float* Wlin = (const float*)d_in[7];
    const float* blin = (const float*)d_in[8];
    float* out = (float*)d_out;
    _Float16* hb = (_Float16*)d_ws;

    void* args[] = { (void*)&x, (void*)&Wih1, (void*)&Whh1, (void*)&b1,
                     (void*)&Wih2, (void*)&Whh2, (void*)&b2,
                     (void*)&Wlin, (void*)&blin, (void*)&out, (void*)&hb };
    hipLaunchCooperativeKernel((const void*)lstm2_ef, dim3(NBLK), dim3(NTHR),
                               args, 0, stream);
}